// Round 2
// baseline (305.209 us; speedup 1.0000x reference)
//
#include <hip/hip_runtime.h>

#define IN_DIM   512
#define OUT_DIM  256
#define N_MID    1280
#define BATCH    16384
#define NT       256
#define XPAD     520      // fallback kernel x stride

// net7 geometry: 256 blocks x 256 threads (4 waves), 64 rows/block, 1 block/CU,
// 1 wave/SIMD -> ~512-reg unified budget.
// R8 lesson: wall = phase-2 serial chain, NOT bandwidth.
// R9: tri rows reg-prefetched (1 ahead), b128 staging, bulk writes.
// R10: 16+16 split resolve + MFMA bridge (bfx), trimmed tri prefetch,
//      apply-B register prefetch (bpre). 252 -> 195 us.
// R11 (this round): (1) tri prefetch depth 4 (was 1) -- the ~120cy ds_read
// latency no longer stalls each column's fan-out; upper prologue rows issued
// under the bridge's latency hops. (2) exp2-domain resolve: tri pre-scaled by
// -log2e at gather, reg init scaled at stage2 read -> removes the v_mul from
// the 768-deep serial sigmoid chain. Bridge/bfx stay in logit domain.

// ---- workspace layout (max geometry: ksteps=48, tpm=64, nch=32) ----
#define EW2_ELEMS ((size_t)48 * 64 * 64 * 8)               // bf16 elems
#define EW2_BYTES (EW2_ELEMS * 2)                          // 3,145,728
#define TRI_OFF   EW2_BYTES
#define TRI_BYTES ((size_t)32 * 1024 * 4)                  // 131,072
#define HDR_OFF   (TRI_OFF + TRI_BYTES)
#define CMAP_OFF  (HDR_OFF + 32)
#define OCOL_OFF  (CMAP_OFF + N_MID * 4)
#define BIASC_OFF (OCOL_OFF + N_MID * 4)
#define BFX_OFF   (BIASC_OFF + N_MID * 4)
#define BFX_BYTES ((size_t)32 * 64 * 8 * 2)                // 32,768
#define WS_NEED   (BFX_OFF + BFX_BYTES)

#define NEG_LOG2E (-1.44269504088896340736f)

typedef __attribute__((ext_vector_type(8))) short  bfrag;
typedef __attribute__((ext_vector_type(4))) float  ffrag;

__device__ __forceinline__ unsigned short f2bf(float f) {
    unsigned int u = __float_as_uint(f);
    u += 0x7FFFu + ((u >> 16) & 1u);       // RNE
    return (unsigned short)(u >> 16);
}

// ============================================================
// Setup A: compact existing columns (1 wave).
// hdr = {Mc, Mpad, unused, nch=Mpad/32, tpm=Mpad/16}
// ============================================================
__global__ void build_maps_kernel(const int* __restrict__ exist,
                                  const float* __restrict__ bias,
                                  int* __restrict__ hdr,
                                  int* __restrict__ cmap,
                                  int* __restrict__ ocol,
                                  float* __restrict__ biasc) {
    const int lane = threadIdx.x;   // 64
    int base = 0;
    for (int r = 0; r < N_MID / 64; ++r) {
        const int i = r * 64 + lane;
        const int e = exist[i];
        const unsigned long long m  = __ballot(e != 0);
        const unsigned long long lt = (lane == 0) ? 0ull : (~0ull >> (64 - lane));
        const int pos = base + __popcll(m & lt);
        if (e) {
            cmap[pos]  = i;
            ocol[pos]  = (i >= N_MID - OUT_DIM) ? (i - (N_MID - OUT_DIM)) : -1;
            biasc[pos] = bias[i];
        }
        base += __popcll(m);
    }
    for (int idx = base + lane; idx < N_MID; idx += 64) {
        cmap[idx] = 0; ocol[idx] = -1; biasc[idx] = 0.f;
    }
    if (lane == 0) {
        const int Mc = base;
        int Mpad;
        if (Mc <= 768) Mpad = 768;
        else if (Mc <= 1024) Mpad = 1024;
        else Mpad = (Mc + 127) & ~127;     // v1 fallback territory
        hdr[0] = Mc; hdr[1] = Mpad; hdr[2] = 0;
        hdr[3] = Mpad / 32; hdr[4] = Mpad / 16;
    }
}

// ============================================================
// Setup B: gather eff_w -> bf16 MFMA B-fragment-major.
// ew2[((kstep*tpm + gt)*64 + lane)*8 + jj] = W[s][c]
//   s = kstep*32 + (lane>>4)*8 + jj, c = gt*16 + (lane&15)
// kstep<16: input rows; kstep>=16: compacted source s2=s-512, zero unless
// s2<c, both <Mc, different 32-chunk (same-chunk handled by tri/bfx).
// ============================================================
__global__ __launch_bounds__(NT)
void gather2_kernel(const float* __restrict__ w, const int* __restrict__ conn,
                    const int* __restrict__ hdr, const int* __restrict__ cmap,
                    unsigned short* __restrict__ ew2) {
    const int Mc = hdr[0], nch = hdr[3], tpm = hdr[4];
    if (tpm > 64) return;                      // v1 fallback case
    const int tid  = blockIdx.x * NT + threadIdx.x;
    const int lane = tid & 63;
    const int gl   = tid >> 6;
    const int gt   = gl % tpm;
    const int kstep = gl / tpm;
    if (kstep >= 16 + nch) return;
    const int c  = gt * 16 + (lane & 15);
    const int k0 = kstep * 32 + ((lane >> 4) << 3);
    unsigned short v[8];
#pragma unroll
    for (int jj = 0; jj < 8; ++jj) {
        const int s = k0 + jj;
        float val = 0.f;
        if (c < Mc) {
            const int cc = cmap[c];
            if (s < IN_DIM) {
                const size_t o = (size_t)s * N_MID + cc;
                val = w[o] * (float)conn[o];
            } else {
                const int s2 = s - IN_DIM;
                if (s2 < Mc && s2 < c && (s2 >> 5) != (c >> 5)) {
                    const size_t o = (size_t)(IN_DIM + cmap[s2]) * N_MID + cc;
                    val = w[o] * (float)conn[o];
                }
            }
        }
        v[jj] = f2bf(val);
    }
    *(uint4*)&ew2[((size_t)(kstep * tpm + gt) * 64 + lane) * 8] = *(uint4*)v;
}

// ============================================================
// Setup C: blocks <128: in-chunk triangle, fp32, PRE-SCALED by -log2e
// (consumed only by the exp2-domain fan-out). tri[j][sl][cl], sl<cl.
// blocks >=128: bfx = in-chunk lower->upper cross-block as bf16 B-fragments
// in LOGIT domain (unscaled):
//   bfx[(j*64+lane)*8+jj] = W[32j + k][32j + 16 + (lane&15)], k=(lane>>4)*8+jj,
//   zero for k>=16 (so MFMA with stale A-quarters 2,3 contributes nothing).
// ============================================================
__global__ __launch_bounds__(NT)
void gather_tri_kernel(const float* __restrict__ w, const int* __restrict__ conn,
                       const int* __restrict__ hdr, const int* __restrict__ cmap,
                       float* __restrict__ tri, unsigned short* __restrict__ bfx) {
    const int Mc = hdr[0], nch = hdr[3];
    const int bx = blockIdx.x;
    if (bx >= 128) {
        const int j = (bx - 128) * 4 + (threadIdx.x >> 6);
        if (j >= nch || j >= 32) return;
        const int lane = threadIdx.x & 63;
        const int cl = lane & 15, qq = lane >> 4;
        const int cg = 32 * j + 16 + cl;
        unsigned short v[8];
#pragma unroll
        for (int jj = 0; jj < 8; ++jj) {
            const int k = qq * 8 + jj;
            float val = 0.f;
            if (k < 16 && cg < Mc) {
                const size_t o = (size_t)(IN_DIM + cmap[32 * j + k]) * N_MID + cmap[cg];
                val = w[o] * (float)conn[o];
            }
            v[jj] = f2bf(val);
        }
        *(uint4*)&bfx[((size_t)j * 64 + lane) * 8] = *(uint4*)v;
        return;
    }
    const int idx = bx * NT + threadIdx.x;   // < 32*1024
    const int j  = idx >> 10;
    if (j >= nch) return;
    const int sl = (idx >> 5) & 31;
    const int cl = idx & 31;
    const int s = j * 32 + sl, c = j * 32 + cl;
    float v = 0.f;
    if (sl < cl && c < Mc) {
        const size_t o = (size_t)(IN_DIM + cmap[s]) * N_MID + cmap[c];
        v = w[o] * (float)conn[o] * NEG_LOG2E;     // exp2-domain fan-out weight
    }
    tri[idx] = v;
}

// helper: static component select from float4 (constant-folded post-unroll)
__device__ __forceinline__ float f4c(const float4& v, int k) {
    return (k == 0) ? v.x : (k == 1) ? v.y : (k == 2) ? v.z : v.w;
}

// ============================================================
// Main kernel (net7): 256 blocks x 256 threads (4 waves), 64 rows/block.
// Mpad = TPW*64. One barrier per chunk. 16+16 split resolver + MFMA bridge.
// Resolve runs in exp2 domain: reg[] = -log2e * logit for pending columns,
// rs (sigmoid+bias, unscaled) after resolve.
// ============================================================
template <int TPW>
__global__ __launch_bounds__(256)
__attribute__((amdgpu_waves_per_eu(1, 1)))
void net7_kernel(const float* __restrict__ x,
                 const unsigned short* __restrict__ ew2,
                 const float* __restrict__ tri_g,
                 const int* __restrict__ hdr,
                 const int* __restrict__ ocol,
                 const float* __restrict__ biasc,
                 const unsigned short* __restrict__ bfx,
                 float* __restrict__ out) {
    if (hdr[1] != TPW * 64) return;
    const int Mc  = hdr[0];
    const int tpm = TPW * 4;                   // Mpad/16
    const int nch = TPW * 2;                   // Mpad/32
    constexpr int D = (TPW <= 12) ? 4 : 2;     // tri prefetch depth (reg budget)

    __shared__ __align__(16) unsigned short xa[4096 * 8];      // 65,536 B
    __shared__ __align__(16) float stage2[32 * 68];            //  8,704 B ([col][row], stride 68)
    __shared__ __align__(16) unsigned short res2[2][2048];     //  8,192 B
    __shared__ __align__(16) float tri_lds[2][1024];           //  8,192 B
    __shared__ float bias_lds[1024];                           //  4,096 B
    __shared__ int   ocol_lds[1024];                           //  4,096 B
    // total ~98.8 KB -> 1 block/CU; 4 waves -> 1 wave/SIMD

    const int t = threadIdx.x, lane = t & 63, w = t >> 6;  // w in 0..3
    const int l15 = lane & 15, q = lane >> 4;
    const int r0 = blockIdx.x * 64;
    const int g0 = w * TPW;

    // ---- stage bias/ocol ----
    for (int i = t; i < TPW * 64; i += 256) {
        bias_lds[i] = biasc[i];
        ocol_lds[i] = ocol[i];
    }
    // ---- zero res2 (bridge reads quarters 2,3 before first write: NaN-safety) ----
    {
        uint4 z; z.x = 0u; z.y = 0u; z.z = 0u; z.w = 0u;
        uint4* r2 = (uint4*)res2;
        for (int i = t; i < 512; i += 256) r2[i] = z;
    }
    // ---- tri chunk 0 (wave 3) ----
    if (w == 3) {
        const float4* src = (const float4*)tri_g;
#pragma unroll
        for (int u = 0; u < 4; ++u)
            *(float4*)&tri_lds[0][(lane + 64 * u) * 4] = src[lane + 64 * u];
    }
    // ---- x -> bf16 A-fragment-contiguous: frag i = (kb*4+rr)*64 + lane2 ----
    for (int i = t; i < 4096; i += 256) {
        const int lane2 = i & 63, rrkb = i >> 6;
        const int rr = rrkb & 3, kb = rrkb >> 2;
        const int qq = lane2 >> 4, ll = lane2 & 15;
        const int row = rr * 16 + ll;
        const int k0 = kb * 32 + qq * 8;
        const float4 f0 = *(const float4*)&x[(size_t)(r0 + row) * IN_DIM + k0];
        const float4 f1 = *(const float4*)&x[(size_t)(r0 + row) * IN_DIM + k0 + 4];
        unsigned short vv[8] = {f2bf(f0.x), f2bf(f0.y), f2bf(f0.z), f2bf(f0.w),
                                f2bf(f1.x), f2bf(f1.y), f2bf(f1.z), f2bf(f1.w)};
        *(uint4*)&xa[(size_t)i * 8] = *(uint4*)vv;
    }
    __syncthreads();

    ffrag acc[TPW][4];
#pragma unroll
    for (int tt = 0; tt < TPW; ++tt)
#pragma unroll
        for (int rr = 0; rr < 4; ++rr) acc[tt][rr] = (ffrag)0.f;

    // ---- phase 1: input GEMM, 16 k-steps ----
#pragma unroll 1
    for (int kb = 0; kb < 16; ++kb) {
        bfrag a[4];
#pragma unroll
        for (int rr = 0; rr < 4; ++rr)
            a[rr] = *(const bfrag*)&xa[((kb * 4 + rr) * 64 + lane) * 8];
#pragma unroll
        for (int tt = 0; tt < TPW; ++tt) {
            if ((g0 + tt) * 16 < Mc) {
                const bfrag b = *(const bfrag*)&ew2[((size_t)(kb * tpm + g0 + tt) * 64 + lane) * 8];
#pragma unroll
                for (int rr = 0; rr < 4; ++rr)
                    acc[tt][rr] = __builtin_amdgcn_mfma_f32_16x16x32_bf16(a[rr], b, acc[tt][rr], 0, 0, 0);
            }
        }
    }

    // ---- phase 2: sequential chunks, ONE barrier each ----
    bfrag bpre[TPW];                            // apply B prefetch (1 chunk ahead)
#pragma unroll 1
    for (int j = 0; j < nch; ++j) {
        const int cbase = 32 * j;
        if (cbase >= Mc) break;                      // uniform

        // in-chunk cross-block B-fragment (cols 16-31 of this chunk)
        const bfrag bc = *(const bfrag*)&bfx[((size_t)j * 64 + lane) * 8];

        if (j > 0) {                                 // apply res_{j-1} (B prefetched)
            const int pr = (j - 1) & 1;
            bfrag a[4];
#pragma unroll
            for (int rr = 0; rr < 4; ++rr)
                a[rr] = *(const bfrag*)&res2[pr][(rr * 64 + lane) * 8];
#pragma unroll
            for (int tt = 0; tt < TPW; ++tt) {
                const int col0 = (g0 + tt) * 16;
                if (col0 >= cbase && col0 < Mc) {
#pragma unroll
                    for (int rr = 0; rr < 4; ++rr)
                        acc[tt][rr] = __builtin_amdgcn_mfma_f32_16x16x32_bf16(a[rr], bpre[tt], acc[tt][rr], 0, 0, 0);
                }
            }
        }
        // prefetch next chunk's apply B-fragments (gate == next apply's gate)
#pragma unroll
        for (int tt = 0; tt < TPW; ++tt) {
            const int col0 = (g0 + tt) * 16;
            if (col0 >= 32 * (j + 1) && col0 < Mc)
                bpre[tt] = *(const bfrag*)&ew2[((size_t)((16 + j) * tpm + g0 + tt) * 64 + lane) * 8];
        }

        const int ow = (2 * j) / TPW;                // owner wave (tiles 2j, 2j+1)
        if (w == ow) {
            // ---- stage lower tile 2j: [col][row] layout, b128 writes ----
#pragma unroll
            for (int tt = 0; tt < TPW; ++tt) {
                if (g0 + tt == 2 * j) {
#pragma unroll
                    for (int rr = 0; rr < 4; ++rr)
                        *(ffrag*)&stage2[l15 * 68 + rr * 16 + 4 * q] = acc[tt][rr];
                }
            }
            const float* trij = tri_lds[j & 1];
            float reg[32];
#pragma unroll
            for (int c = 0; c < 16; ++c)
                reg[c] = stage2[c * 68 + lane] * NEG_LOG2E;

            float4 tr[D][8];                         // tri row D-deep pipeline
            // prologue: rows 0..D-1 (row r used elems k>=r+1 -> u>=(r+1)>>2)
#pragma unroll
            for (int r = 0; r < D; ++r)
#pragma unroll
                for (int u = (r + 1) >> 2; u < 4; ++u)
                    tr[r][u] = *(const float4*)&trij[r * 32 + u * 4];

            // ---- resolve cols 0-15 (lower triangle only, exp2 domain) ----
#pragma unroll
            for (int c = 0; c < 16; ++c) {
                const float s  = __fdividef(1.f, 1.f + exp2f(reg[c]));
                const float rs = s + bias_lds[cbase + c];
                reg[c] = rs;
#pragma unroll
                for (int k = c + 1; k < 16; ++k)
                    reg[k] = fmaf(rs, f4c(tr[c & (D - 1)][k >> 2], k & 3), reg[k]);
                // prefetch row c+D (after fan-out: frees buffer (c)&(D-1))
                const int pf = c + D;
                if (pf < 16) {
#pragma unroll
                    for (int u = (pf + 1) >> 2; u < 4; ++u)
                        tr[pf & (D - 1)][u] = *(const float4*)&trij[pf * 32 + u * 4];
                }
            }
            // ---- upper prologue rows 16..16+D-1 (latency hides under bridge) ----
#pragma unroll
            for (int r = 16; r < 16 + D; ++r)
#pragma unroll
                for (int u = (r + 1) >> 2; u < 8; ++u)
                    tr[r & (D - 1)][u] = *(const float4*)&trij[r * 32 + u * 4];

            // ---- pack lower rs -> res2[j&1] quarters 0,1 (A-frag layout) ----
            unsigned short* resb = res2[j & 1];
            const int rowA = (q * 64 + l15) * 8;
#pragma unroll
            for (int qA = 0; qA < 2; ++qA) {
                unsigned int u[4];
#pragma unroll
                for (int i = 0; i < 4; ++i)
                    u[i] = (unsigned int)f2bf(reg[qA * 8 + 2 * i]) |
                           ((unsigned int)f2bf(reg[qA * 8 + 2 * i + 1]) << 16);
                *(uint4*)&resb[rowA + qA * 128] = *(uint4*)u;
            }
            // ---- MFMA bridge: lower results -> upper tile (k>=16 of bc is 0) ----
            bfrag aB[4];
#pragma unroll
            for (int rr = 0; rr < 4; ++rr)
                aB[rr] = *(const bfrag*)&resb[(rr * 64 + lane) * 8];
#pragma unroll
            for (int tt = 0; tt < TPW; ++tt) {
                if (g0 + tt == 2 * j + 1) {
#pragma unroll
                    for (int rr = 0; rr < 4; ++rr)
                        acc[tt][rr] = __builtin_amdgcn_mfma_f32_16x16x32_bf16(aB[rr], bc, acc[tt][rr], 0, 0, 0);
#pragma unroll
                    for (int rr = 0; rr < 4; ++rr)
                        *(ffrag*)&stage2[(16 + l15) * 68 + rr * 16 + 4 * q] = acc[tt][rr];
                }
            }
#pragma unroll
            for (int c = 16; c < 32; ++c)
                reg[c] = stage2[c * 68 + lane] * NEG_LOG2E;

            // ---- resolve cols 16-31 (upper triangle only, exp2 domain) ----
#pragma unroll
            for (int c = 16; c < 32; ++c) {
                const float s  = __fdividef(1.f, 1.f + exp2f(reg[c]));
                const float rs = s + bias_lds[cbase + c];
                reg[c] = rs;
#pragma unroll
                for (int k = c + 1; k < 32; ++k)
                    reg[k] = fmaf(rs, f4c(tr[c & (D - 1)][k >> 2], k & 3), reg[k]);
                const int pf = c + D;
                if (pf < 32) {
#pragma unroll
                    for (int u = (pf + 1) >> 2; u < 8; ++u)
                        tr[pf & (D - 1)][u] = *(const float4*)&trij[pf * 32 + u * 4];
                }
            }
            // ---- pack upper rs -> quarters 2,3 ----
#pragma unroll
            for (int qA = 2; qA < 4; ++qA) {
                unsigned int u[4];
#pragma unroll
                for (int i = 0; i < 4; ++i)
                    u[i] = (unsigned int)f2bf(reg[qA * 8 + 2 * i]) |
                           ((unsigned int)f2bf(reg[qA * 8 + 2 * i + 1]) << 16);
                *(uint4*)&resb[rowA + qA * 128] = *(uint4*)u;
            }
            // ---- bulk out stores ----
#pragma unroll
            for (int c = 0; c < 32; ++c) {
                const int oc = ocol_lds[cbase + c];  // uniform
                if (oc >= 0)
                    out[(size_t)(r0 + lane) * OUT_DIM + oc] = reg[c];
            }
        } else if (w == ((ow + 2) & 3)) {
            // prefetch tri for chunk j+1 (overlaps resolve)
            const int jn = j + 1;
            if (jn < nch && 32 * jn < Mc) {
                const float4* src = (const float4*)(tri_g + (size_t)jn * 1024);
#pragma unroll
                for (int u = 0; u < 4; ++u)
                    *(float4*)&tri_lds[jn & 1][(lane + 64 * u) * 4] = src[lane + 64 * u];
            }
        }
        __syncthreads();                             // the ONE barrier
    }
}

// ============================================================
// Fallback (Mc > 1024 or tiny ws): round-1 monolithic fp32 kernel.
// ============================================================
__global__ __launch_bounds__(NT, 4)
void net_v1_kernel(const float* __restrict__ x,
                   const float* __restrict__ wsrc,
                   const int* __restrict__ conn,
                   const float* __restrict__ bias,
                   const int* __restrict__ exist,
                   const int* __restrict__ hdr,   // null = always run
                   float* __restrict__ out) {
    if (hdr && hdr[1] <= 1024) return;
    __shared__ float xs[16 * XPAD];
    __shared__ float res_s[2][16];
    float* bias_s  = xs;
    float* exist_s = xs + N_MID;
    const int t = threadIdx.x, rg = t & 3, cg = t >> 2;
    const int r0 = blockIdx.x * 16;
    const int c0 = cg * 20;
    {
        const float4* xg = (const float4*)(x + (size_t)r0 * IN_DIM);
        for (int idx = t; idx < 16 * IN_DIM / 4; idx += NT) {
            const int r = idx >> 7, jj = idx & 127;
            *(float4*)&xs[r * XPAD + jj * 4] = xg[idx];
        }
    }
    __syncthreads();
    float acc[4][20];
#pragma unroll
    for (int a = 0; a < 4; ++a)
#pragma unroll
        for (int k = 0; k < 20; ++k) acc[a][k] = 0.f;
    for (int j = 0; j < IN_DIM; ++j) {
        const size_t woff = (size_t)j * N_MID + c0;
        const float xv0 = xs[rg * XPAD + j];
        const float xv1 = xs[(rg + 4) * XPAD + j];
        const float xv2 = xs[(rg + 8) * XPAD + j];
        const float xv3 = xs[(rg + 12) * XPAD + j];
#pragma unroll
        for (int qq = 0; qq < 5; ++qq) {
            float4 w4 = *(const float4*)(wsrc + woff + qq * 4);
            const int4 c4 = *(const int4*)(conn + woff + qq * 4);
            w4.x *= (float)c4.x; w4.y *= (float)c4.y;
            w4.z *= (float)c4.z; w4.w *= (float)c4.w;
            const float wq[4] = {w4.x, w4.y, w4.z, w4.w};
#pragma unroll
            for (int u = 0; u < 4; ++u) {
                const int k = qq * 4 + u;
                acc[0][k] = fmaf(xv0, wq[u], acc[0][k]);
                acc[1][k] = fmaf(xv1, wq[u], acc[1][k]);
                acc[2][k] = fmaf(xv2, wq[u], acc[2][k]);
                acc[3][k] = fmaf(xv3, wq[u], acc[3][k]);
            }
        }
    }
    __syncthreads();
    for (int idx = t; idx < N_MID; idx += NT) {
        bias_s[idx]  = bias[idx];
        exist_s[idx] = (float)exist[idx];
    }
    __syncthreads();
    int p = 0;
    for (int bb = 0; bb < 64; ++bb) {
#pragma unroll
        for (int kk = 0; kk < 20; ++kk) {
            const int i = bb * 20 + kk;
            const float e = exist_s[i];
            if (e != 0.f) {
                if (cg == bb) {
                    const float bv = bias_s[i];
#pragma unroll
                    for (int a = 0; a < 4; ++a) {
                        const float v = acc[a][kk];
                        const float s = __fdividef(1.f, 1.f + __expf(-v));
                        const float res = (s + bv) * e;
                        res_s[p][rg + 4 * a] = res;
                        if (i >= N_MID - OUT_DIM)
                            out[(size_t)(r0 + rg + 4 * a) * OUT_DIM + (i - (N_MID - OUT_DIM))] = res;
                    }
                }
                __syncthreads();
                const float rv0 = res_s[p][rg];
                const float rv1 = res_s[p][rg + 4];
                const float rv2 = res_s[p][rg + 8];
                const float rv3 = res_s[p][rg + 12];
                const size_t woff = (size_t)(IN_DIM + i) * N_MID + c0;
                if (cg > bb) {
#pragma unroll
                    for (int qq = 0; qq < 5; ++qq) {
                        float4 w4 = *(const float4*)(wsrc + woff + qq * 4);
                        const int4 c4 = *(const int4*)(conn + woff + qq * 4);
                        w4.x *= (float)c4.x; w4.y *= (float)c4.y;
                        w4.z *= (float)c4.z; w4.w *= (float)c4.w;
                        const float wq[4] = {w4.x, w4.y, w4.z, w4.w};
#pragma unroll
                        for (int u = 0; u < 4; ++u) {
                            const int k = qq * 4 + u;
                            acc[0][k] = fmaf(rv0, wq[u], acc[0][k]);
                            acc[1][k] = fmaf(rv1, wq[u], acc[1][k]);
                            acc[2][k] = fmaf(rv2, wq[u], acc[2][k]);
                            acc[3][k] = fmaf(rv3, wq[u], acc[3][k]);
                        }
                    }
                } else if (cg == bb) {
#pragma unroll
                    for (int k = kk + 1; k < 20; ++k) {
                        float ww = wsrc[woff + k] * (float)conn[woff + k];
                        acc[0][k] = fmaf(rv0, ww, acc[0][k]);
                        acc[1][k] = fmaf(rv1, ww, acc[1][k]);
                        acc[2][k] = fmaf(rv2, ww, acc[2][k]);
                        acc[3][k] = fmaf(rv3, ww, acc[3][k]);
                    }
                }
                p ^= 1;
            }
        }
    }
}

extern "C" void kernel_launch(void* const* d_in, const int* in_sizes, int n_in,
                              void* d_out, int out_size, void* d_ws, size_t ws_size,
                              hipStream_t stream) {
    const float* x      = (const float*)d_in[0];
    const float* weight = (const float*)d_in[1];
    const float* bias   = (const float*)d_in[2];
    const int*   conn   = (const int*)d_in[3];
    const int*   exist  = (const int*)d_in[4];
    float*       out    = (float*)d_out;

    if (ws_size >= WS_NEED) {
        char* ws = (char*)d_ws;
        unsigned short* ew2  = (unsigned short*)ws;
        float*          tri  = (float*)(ws + TRI_OFF);
        int*            hdr  = (int*)(ws + HDR_OFF);
        int*            cmap = (int*)(ws + CMAP_OFF);
        int*            ocolp= (int*)(ws + OCOL_OFF);
        float*          bsc  = (float*)(ws + BIASC_OFF);
        unsigned short* bfx  = (unsigned short*)(ws + BFX_OFF);

        build_maps_kernel<<<1, 64, 0, stream>>>(exist, bias, hdr, cmap, ocolp, bsc);
        gather2_kernel<<<768, NT, 0, stream>>>(weight, conn, hdr, cmap, ew2);
        gather_tri_kernel<<<136, NT, 0, stream>>>(weight, conn, hdr, cmap, tri, bfx);
        net7_kernel<12><<<256, 256, 0, stream>>>(x, ew2, tri, hdr, ocolp, bsc, bfx, out);
        net7_kernel<16><<<256, 256, 0, stream>>>(x, ew2, tri, hdr, ocolp, bsc, bfx, out);
        net_v1_kernel<<<BATCH / 16, NT, 0, stream>>>(x, weight, conn, bias, exist, hdr, out);
    } else {
        net_v1_kernel<<<BATCH / 16, NT, 0, stream>>>(x, weight, conn, bias, exist, nullptr, out);
    }
}

// Round 3
// 285.073 us; speedup vs baseline: 1.0706x; 1.0706x over previous
//
#include <hip/hip_runtime.h>

#define IN_DIM   512
#define OUT_DIM  256
#define N_MID    1280
#define BATCH    16384
#define NT       256
#define XPAD     520      // fallback kernel x stride

// net7 geometry: 256 blocks x 256 threads (4 waves), 64 rows/block, 1 block/CU,
// 1 wave/SIMD -> ~512-reg unified budget.
// R8: wall = phase-2 serial chain, NOT bandwidth.
// R9: tri rows reg-prefetched (1 ahead, issued BEFORE sigmoid), b128 staging.
// R10: 16+16 split resolve + MFMA bridge (bfx), apply-B prefetch. 252->195us.
// R11 FAILED (+10us): OCML exp2f subnormal fixup on chain; depth-4 prefetch
//   added issue work. Reverted.
// R12: R10 structure + (1) exp2 domain via SETUP-side prescale of ew2/tri/bfx
//   by -log2e (zero added ops in net7; chain loses the mul), (2) raw v_exp_f32
//   + v_rcp_f32 (no OCML, no x1.0 mul), (3) v_cvt_pk_bf16_f32 packs (res2 pack
//   112 ops -> 16 instrs/chunk), (4) b128 out stores, (5) gather2+tri+bfx in
//   ONE dispatch.

// ---- workspace layout (max geometry: ksteps=48, tpm=64, nch=32) ----
#define EW2_ELEMS ((size_t)48 * 64 * 64 * 8)               // bf16 elems
#define EW2_BYTES (EW2_ELEMS * 2)                          // 3,145,728
#define TRI_OFF   EW2_BYTES
#define TRI_BYTES ((size_t)32 * 1024 * 4)                  // 131,072
#define HDR_OFF   (TRI_OFF + TRI_BYTES)
#define CMAP_OFF  (HDR_OFF + 32)
#define OCOL_OFF  (CMAP_OFF + N_MID * 4)
#define BIASC_OFF (OCOL_OFF + N_MID * 4)
#define BFX_OFF   (BIASC_OFF + N_MID * 4)
#define BFX_BYTES ((size_t)32 * 64 * 8 * 2)                // 32,768
#define WS_NEED   (BFX_OFF + BFX_BYTES)

#define NEG_LOG2E (-1.44269504088896340736f)

typedef __attribute__((ext_vector_type(8))) short  bfrag;
typedef __attribute__((ext_vector_type(4))) float  ffrag;

__device__ __forceinline__ unsigned short f2bf(float f) {
    unsigned int u = __float_as_uint(f);
    u += 0x7FFFu + ((u >> 16) & 1u);       // RNE
    return (unsigned short)(u >> 16);
}

// raw HW exp2 (no OCML subnormal fixup -- R11 lesson)
__device__ __forceinline__ float fast_exp2(float x) {
#if __has_builtin(__builtin_amdgcn_exp2f)
    return __builtin_amdgcn_exp2f(x);
#else
    float r;
    asm("v_exp_f32 %0, %1" : "=v"(r) : "v"(x));
    return r;
#endif
}

// raw HW rcp (single instr; __fdividef(1,x) keeps a x1.0 mul on the chain)
__device__ __forceinline__ float fast_rcp(float x) {
#if __has_builtin(__builtin_amdgcn_rcpf)
    return __builtin_amdgcn_rcpf(x);
#else
    float r;
    asm("v_rcp_f32 %0, %1" : "=v"(r) : "v"(x));
    return r;
#endif
}

// packed f32x2 -> bf16x2 (RNE), one instr replaces ~7 scalar ops
__device__ __forceinline__ unsigned int cvt_pk_bf16(float lo, float hi) {
    unsigned int r;
    asm("v_cvt_pk_bf16_f32 %0, %1, %2" : "=v"(r) : "v"(lo), "v"(hi));
    return r;
}

// ============================================================
// Setup A: compact existing columns (1 wave).
// hdr = {Mc, Mpad, unused, nch=Mpad/32, tpm=Mpad/16}
// ============================================================
__global__ void build_maps_kernel(const int* __restrict__ exist,
                                  const float* __restrict__ bias,
                                  int* __restrict__ hdr,
                                  int* __restrict__ cmap,
                                  int* __restrict__ ocol,
                                  float* __restrict__ biasc) {
    const int lane = threadIdx.x;   // 64
    int base = 0;
    for (int r = 0; r < N_MID / 64; ++r) {
        const int i = r * 64 + lane;
        const int e = exist[i];
        const unsigned long long m  = __ballot(e != 0);
        const unsigned long long lt = (lane == 0) ? 0ull : (~0ull >> (64 - lane));
        const int pos = base + __popcll(m & lt);
        if (e) {
            cmap[pos]  = i;
            ocol[pos]  = (i >= N_MID - OUT_DIM) ? (i - (N_MID - OUT_DIM)) : -1;
            biasc[pos] = bias[i];
        }
        base += __popcll(m);
    }
    for (int idx = base + lane; idx < N_MID; idx += 64) {
        cmap[idx] = 0; ocol[idx] = -1; biasc[idx] = 0.f;
    }
    if (lane == 0) {
        const int Mc = base;
        int Mpad;
        if (Mc <= 768) Mpad = 768;
        else if (Mc <= 1024) Mpad = 1024;
        else Mpad = (Mc + 127) & ~127;     // v1 fallback territory
        hdr[0] = Mc; hdr[1] = Mpad; hdr[2] = 0;
        hdr[3] = Mpad / 32; hdr[4] = Mpad / 16;
    }
}

// ============================================================
// Setup B (merged, ONE dispatch): all weights PRE-SCALED by -log2e so the
// resolver runs in exp2 domain with zero extra ops.
//  blocks [0,768):   ew2 gather -> bf16 MFMA B-fragment-major.
//    ew2[((kstep*tpm + gt)*64 + lane)*8 + jj] = -log2e * W[s][c]
//    s = kstep*32 + (lane>>4)*8 + jj, c = gt*16 + (lane&15)
//    kstep<16: input rows; kstep>=16: compacted source s2=s-512, zero unless
//    s2<c, both <Mc, different 32-chunk (same-chunk handled by tri/bfx).
//  blocks [768,896): tri = in-chunk triangle, fp32, scaled. tri[j][sl][cl], sl<cl.
//  blocks [896,904): bfx = in-chunk lower->upper cross block, bf16 B-frags,
//    scaled, zero for k>=16 (stale res2 quarters 2,3 multiply by zero).
// ============================================================
__global__ __launch_bounds__(NT)
void gather_all_kernel(const float* __restrict__ w, const int* __restrict__ conn,
                       const int* __restrict__ hdr, const int* __restrict__ cmap,
                       unsigned short* __restrict__ ew2, float* __restrict__ tri,
                       unsigned short* __restrict__ bfx) {
    const int Mc = hdr[0], nch = hdr[3], tpm = hdr[4];
    const int bx = blockIdx.x;
    if (bx < 768) {
        if (tpm > 64) return;                      // v1 fallback case
        const int tid  = bx * NT + threadIdx.x;
        const int lane = tid & 63;
        const int gl   = tid >> 6;
        const int gt   = gl % tpm;
        const int kstep = gl / tpm;
        if (kstep >= 16 + nch) return;
        const int c  = gt * 16 + (lane & 15);
        const int k0 = kstep * 32 + ((lane >> 4) << 3);
        unsigned short v[8];
#pragma unroll
        for (int jj = 0; jj < 8; ++jj) {
            const int s = k0 + jj;
            float val = 0.f;
            if (c < Mc) {
                const int cc = cmap[c];
                if (s < IN_DIM) {
                    const size_t o = (size_t)s * N_MID + cc;
                    val = w[o] * (float)conn[o] * NEG_LOG2E;
                } else {
                    const int s2 = s - IN_DIM;
                    if (s2 < Mc && s2 < c && (s2 >> 5) != (c >> 5)) {
                        const size_t o = (size_t)(IN_DIM + cmap[s2]) * N_MID + cc;
                        val = w[o] * (float)conn[o] * NEG_LOG2E;
                    }
                }
            }
            v[jj] = f2bf(val);
        }
        *(uint4*)&ew2[((size_t)(kstep * tpm + gt) * 64 + lane) * 8] = *(uint4*)v;
    } else if (bx < 896) {
        if (tpm > 64) return;
        const int idx = (bx - 768) * NT + threadIdx.x;   // < 32*1024
        const int j  = idx >> 10;
        if (j >= nch) return;
        const int sl = (idx >> 5) & 31;
        const int cl = idx & 31;
        const int s = j * 32 + sl, c = j * 32 + cl;
        float v = 0.f;
        if (sl < cl && c < Mc) {
            const size_t o = (size_t)(IN_DIM + cmap[s]) * N_MID + cmap[c];
            v = w[o] * (float)conn[o] * NEG_LOG2E;
        }
        tri[idx] = v;
    } else {
        if (tpm > 64) return;
        const int j = (bx - 896) * 4 + (threadIdx.x >> 6);
        if (j >= nch || j >= 32) return;
        const int lane = threadIdx.x & 63;
        const int cl = lane & 15, qq = lane >> 4;
        const int cg = 32 * j + 16 + cl;
        unsigned short v[8];
#pragma unroll
        for (int jj = 0; jj < 8; ++jj) {
            const int k = qq * 8 + jj;
            float val = 0.f;
            if (k < 16 && cg < Mc) {
                const size_t o = (size_t)(IN_DIM + cmap[32 * j + k]) * N_MID + cmap[cg];
                val = w[o] * (float)conn[o] * NEG_LOG2E;
            }
            v[jj] = f2bf(val);
        }
        *(uint4*)&bfx[((size_t)j * 64 + lane) * 8] = *(uint4*)v;
    }
}

// helper: static component select from float4 (constant-folded post-unroll)
__device__ __forceinline__ float f4c(const float4& v, int k) {
    return (k == 0) ? v.x : (k == 1) ? v.y : (k == 2) ? v.z : v.w;
}

// ============================================================
// Main kernel (net7): 256 blocks x 256 threads (4 waves), 64 rows/block.
// Mpad = TPW*64. One barrier per chunk. 16+16 split resolver + MFMA bridge.
// All W paths pre-scaled by -log2e -> acc holds -log2e*logit; chain is
// exp2 -> add 1 -> rcp -> add bias -> fma.
// ============================================================
template <int TPW>
__global__ __launch_bounds__(256)
__attribute__((amdgpu_waves_per_eu(1, 1)))
void net7_kernel(const float* __restrict__ x,
                 const unsigned short* __restrict__ ew2,
                 const float* __restrict__ tri_g,
                 const int* __restrict__ hdr,
                 const int* __restrict__ ocol,
                 const float* __restrict__ biasc,
                 const unsigned short* __restrict__ bfx,
                 float* __restrict__ out) {
    if (hdr[1] != TPW * 64) return;
    const int Mc  = hdr[0];
    const int tpm = TPW * 4;                   // Mpad/16
    const int nch = TPW * 2;                   // Mpad/32

    __shared__ __align__(16) unsigned short xa[4096 * 8];      // 65,536 B
    __shared__ __align__(16) float stage2[32 * 68];            //  8,704 B ([col][row], stride 68)
    __shared__ __align__(16) unsigned short res2[2][2048];     //  8,192 B
    __shared__ __align__(16) float tri_lds[2][1024];           //  8,192 B
    __shared__ float bias_lds[1024];                           //  4,096 B
    __shared__ int   ocol_lds[1024];                           //  4,096 B
    // total ~98.8 KB -> 1 block/CU; 4 waves -> 1 wave/SIMD

    const int t = threadIdx.x, lane = t & 63, w = t >> 6;  // w in 0..3
    const int l15 = lane & 15, q = lane >> 4;
    const int r0 = blockIdx.x * 64;
    const int g0 = w * TPW;

    // ---- stage bias/ocol ----
    for (int i = t; i < TPW * 64; i += 256) {
        bias_lds[i] = biasc[i];
        ocol_lds[i] = ocol[i];
    }
    // ---- zero res2 (bridge reads quarters 2,3 before first write: NaN-safety) ----
    {
        uint4 z; z.x = 0u; z.y = 0u; z.z = 0u; z.w = 0u;
        uint4* r2 = (uint4*)res2;
        for (int i = t; i < 512; i += 256) r2[i] = z;
    }
    // ---- tri chunk 0 (wave 3) ----
    if (w == 3) {
        const float4* src = (const float4*)tri_g;
#pragma unroll
        for (int u = 0; u < 4; ++u)
            *(float4*)&tri_lds[0][(lane + 64 * u) * 4] = src[lane + 64 * u];
    }
    // ---- x -> bf16 A-fragment-contiguous: frag i = (kb*4+rr)*64 + lane2 ----
    for (int i = t; i < 4096; i += 256) {
        const int lane2 = i & 63, rrkb = i >> 6;
        const int rr = rrkb & 3, kb = rrkb >> 2;
        const int qq = lane2 >> 4, ll = lane2 & 15;
        const int row = rr * 16 + ll;
        const int k0 = kb * 32 + qq * 8;
        const float4 f0 = *(const float4*)&x[(size_t)(r0 + row) * IN_DIM + k0];
        const float4 f1 = *(const float4*)&x[(size_t)(r0 + row) * IN_DIM + k0 + 4];
        unsigned int uu[4] = {cvt_pk_bf16(f0.x, f0.y), cvt_pk_bf16(f0.z, f0.w),
                              cvt_pk_bf16(f1.x, f1.y), cvt_pk_bf16(f1.z, f1.w)};
        *(uint4*)&xa[(size_t)i * 8] = *(uint4*)uu;
    }
    __syncthreads();

    ffrag acc[TPW][4];
#pragma unroll
    for (int tt = 0; tt < TPW; ++tt)
#pragma unroll
        for (int rr = 0; rr < 4; ++rr) acc[tt][rr] = (ffrag)0.f;

    // ---- phase 1: input GEMM, 16 k-steps ----
#pragma unroll 1
    for (int kb = 0; kb < 16; ++kb) {
        bfrag a[4];
#pragma unroll
        for (int rr = 0; rr < 4; ++rr)
            a[rr] = *(const bfrag*)&xa[((kb * 4 + rr) * 64 + lane) * 8];
#pragma unroll
        for (int tt = 0; tt < TPW; ++tt) {
            if ((g0 + tt) * 16 < Mc) {
                const bfrag b = *(const bfrag*)&ew2[((size_t)(kb * tpm + g0 + tt) * 64 + lane) * 8];
#pragma unroll
                for (int rr = 0; rr < 4; ++rr)
                    acc[tt][rr] = __builtin_amdgcn_mfma_f32_16x16x32_bf16(a[rr], b, acc[tt][rr], 0, 0, 0);
            }
        }
    }

    // ---- phase 2: sequential chunks, ONE barrier each ----
    bfrag bpre[TPW];                            // apply B prefetch (1 chunk ahead)
#pragma unroll 1
    for (int j = 0; j < nch; ++j) {
        const int cbase = 32 * j;
        if (cbase >= Mc) break;                      // uniform

        // in-chunk cross-block B-fragment (cols 16-31 of this chunk)
        const bfrag bc = *(const bfrag*)&bfx[((size_t)j * 64 + lane) * 8];

        if (j > 0) {                                 // apply res_{j-1} (B prefetched)
            const int pr = (j - 1) & 1;
            bfrag a[4];
#pragma unroll
            for (int rr = 0; rr < 4; ++rr)
                a[rr] = *(const bfrag*)&res2[pr][(rr * 64 + lane) * 8];
#pragma unroll
            for (int tt = 0; tt < TPW; ++tt) {
                const int col0 = (g0 + tt) * 16;
                if (col0 >= cbase && col0 < Mc) {
#pragma unroll
                    for (int rr = 0; rr < 4; ++rr)
                        acc[tt][rr] = __builtin_amdgcn_mfma_f32_16x16x32_bf16(a[rr], bpre[tt], acc[tt][rr], 0, 0, 0);
                }
            }
        }
        // prefetch next chunk's apply B-fragments (gate == next apply's gate)
#pragma unroll
        for (int tt = 0; tt < TPW; ++tt) {
            const int col0 = (g0 + tt) * 16;
            if (col0 >= 32 * (j + 1) && col0 < Mc)
                bpre[tt] = *(const bfrag*)&ew2[((size_t)((16 + j) * tpm + g0 + tt) * 64 + lane) * 8];
        }

        const int ow = (2 * j) / TPW;                // owner wave (tiles 2j, 2j+1)
        if (w == ow) {
            // ---- stage lower tile 2j: [col][row] layout, b128 writes ----
#pragma unroll
            for (int tt = 0; tt < TPW; ++tt) {
                if (g0 + tt == 2 * j) {
#pragma unroll
                    for (int rr = 0; rr < 4; ++rr)
                        *(ffrag*)&stage2[l15 * 68 + rr * 16 + 4 * q] = acc[tt][rr];
                }
            }
            const float* trij = tri_lds[j & 1];
            float reg[32];
#pragma unroll
            for (int c = 0; c < 16; ++c) reg[c] = stage2[c * 68 + lane];

            float4 tr[2][8];                         // tri row double-buffer
#pragma unroll
            for (int u = 0; u < 4; ++u) tr[0][u] = *(const float4*)&trij[u * 4];

            // ---- resolve cols 0-15 (lower triangle only, exp2 domain) ----
#pragma unroll
            for (int c = 0; c < 16; ++c) {
                const int cb = c & 1;
                if (c < 15) {
#pragma unroll
                    for (int u = (c + 2) >> 2; u < 4; ++u)
                        tr[cb ^ 1][u] = *(const float4*)&trij[(c + 1) * 32 + u * 4];
                }
                const float e  = fast_exp2(reg[c]);
                const float s  = fast_rcp(1.f + e);
                const float rs = s + bias_lds[cbase + c];
                reg[c] = rs;
#pragma unroll
                for (int k = c + 1; k < 16; ++k)
                    reg[k] = fmaf(rs, f4c(tr[cb][k >> 2], k & 3), reg[k]);
            }
            // ---- pack lower rs -> res2[j&1] quarters 0,1 (A-frag layout) ----
            unsigned short* resb = res2[j & 1];
            const int rowA = (q * 64 + l15) * 8;
#pragma unroll
            for (int qA = 0; qA < 2; ++qA) {
                unsigned int u[4];
#pragma unroll
                for (int i = 0; i < 4; ++i)
                    u[i] = cvt_pk_bf16(reg[qA * 8 + 2 * i], reg[qA * 8 + 2 * i + 1]);
                *(uint4*)&resb[rowA + qA * 128] = *(uint4*)u;
            }
            // ---- MFMA bridge: lower results -> upper tile (k>=16 of bc is 0) ----
            bfrag aB[4];
#pragma unroll
            for (int rr = 0; rr < 4; ++rr)
                aB[rr] = *(const bfrag*)&resb[(rr * 64 + lane) * 8];
#pragma unroll
            for (int tt = 0; tt < TPW; ++tt) {
                if (g0 + tt == 2 * j + 1) {
#pragma unroll
                    for (int rr = 0; rr < 4; ++rr)
                        acc[tt][rr] = __builtin_amdgcn_mfma_f32_16x16x32_bf16(aB[rr], bc, acc[tt][rr], 0, 0, 0);
#pragma unroll
                    for (int rr = 0; rr < 4; ++rr)
                        *(ffrag*)&stage2[(16 + l15) * 68 + rr * 16 + 4 * q] = acc[tt][rr];
                }
            }
#pragma unroll
            for (int c = 16; c < 32; ++c) reg[c] = stage2[c * 68 + lane];
#pragma unroll
            for (int u = 4; u < 8; ++u) tr[0][u] = *(const float4*)&trij[16 * 32 + u * 4];

            // ---- resolve cols 16-31 (upper triangle only, exp2 domain) ----
#pragma unroll
            for (int c = 16; c < 32; ++c) {
                const int cb = c & 1;
                if (c < 31) {
#pragma unroll
                    for (int u = (c + 2) >> 2; u < 8; ++u)
                        tr[cb ^ 1][u] = *(const float4*)&trij[(c + 1) * 32 + u * 4];
                }
                const float e  = fast_exp2(reg[c]);
                const float s  = fast_rcp(1.f + e);
                const float rs = s + bias_lds[cbase + c];
                reg[c] = rs;
#pragma unroll
                for (int k = c + 1; k < 32; ++k)
                    reg[k] = fmaf(rs, f4c(tr[cb][k >> 2], k & 3), reg[k]);
            }
            // ---- pack upper rs -> quarters 2,3 ----
#pragma unroll
            for (int qA = 2; qA < 4; ++qA) {
                unsigned int u[4];
#pragma unroll
                for (int i = 0; i < 4; ++i)
                    u[i] = cvt_pk_bf16(reg[qA * 8 + 2 * i], reg[qA * 8 + 2 * i + 1]);
                *(uint4*)&resb[rowA + qA * 128] = *(uint4*)u;
            }
            // ---- bulk out stores (b128 when 4 consecutive aligned ocols) ----
#pragma unroll
            for (int c4 = 0; c4 < 8; ++c4) {
                const int oc0 = ocol_lds[cbase + c4 * 4];        // uniform
                const int oc3 = ocol_lds[cbase + c4 * 4 + 3];
                if (oc0 >= 0 && oc3 == oc0 + 3 && (oc0 & 3) == 0) {
                    const float4 v = make_float4(reg[c4 * 4], reg[c4 * 4 + 1],
                                                 reg[c4 * 4 + 2], reg[c4 * 4 + 3]);
                    *(float4*)&out[(size_t)(r0 + lane) * OUT_DIM + oc0] = v;
                } else {
#pragma unroll
                    for (int c = c4 * 4; c < c4 * 4 + 4; ++c) {
                        const int oc = ocol_lds[cbase + c];
                        if (oc >= 0)
                            out[(size_t)(r0 + lane) * OUT_DIM + oc] = reg[c];
                    }
                }
            }
        } else if (w == ((ow + 2) & 3)) {
            // prefetch tri for chunk j+1 (overlaps resolve)
            const int jn = j + 1;
            if (jn < nch && 32 * jn < Mc) {
                const float4* src = (const float4*)(tri_g + (size_t)jn * 1024);
#pragma unroll
                for (int u = 0; u < 4; ++u)
                    *(float4*)&tri_lds[jn & 1][(lane + 64 * u) * 4] = src[lane + 64 * u];
            }
        }
        __syncthreads();                             // the ONE barrier
    }
}

// ============================================================
// Fallback (Mc > 1024 or tiny ws): round-1 monolithic fp32 kernel.
// ============================================================
__global__ __launch_bounds__(NT, 4)
void net_v1_kernel(const float* __restrict__ x,
                   const float* __restrict__ wsrc,
                   const int* __restrict__ conn,
                   const float* __restrict__ bias,
                   const int* __restrict__ exist,
                   const int* __restrict__ hdr,   // null = always run
                   float* __restrict__ out) {
    if (hdr && hdr[1] <= 1024) return;
    __shared__ float xs[16 * XPAD];
    __shared__ float res_s[2][16];
    float* bias_s  = xs;
    float* exist_s = xs + N_MID;
    const int t = threadIdx.x, rg = t & 3, cg = t >> 2;
    const int r0 = blockIdx.x * 16;
    const int c0 = cg * 20;
    {
        const float4* xg = (const float4*)(x + (size_t)r0 * IN_DIM);
        for (int idx = t; idx < 16 * IN_DIM / 4; idx += NT) {
            const int r = idx >> 7, jj = idx & 127;
            *(float4*)&xs[r * XPAD + jj * 4] = xg[idx];
        }
    }
    __syncthreads();
    float acc[4][20];
#pragma unroll
    for (int a = 0; a < 4; ++a)
#pragma unroll
        for (int k = 0; k < 20; ++k) acc[a][k] = 0.f;
    for (int j = 0; j < IN_DIM; ++j) {
        const size_t woff = (size_t)j * N_MID + c0;
        const float xv0 = xs[rg * XPAD + j];
        const float xv1 = xs[(rg + 4) * XPAD + j];
        const float xv2 = xs[(rg + 8) * XPAD + j];
        const float xv3 = xs[(rg + 12) * XPAD + j];
#pragma unroll
        for (int qq = 0; qq < 5; ++qq) {
            float4 w4 = *(const float4*)(wsrc + woff + qq * 4);
            const int4 c4 = *(const int4*)(conn + woff + qq * 4);
            w4.x *= (float)c4.x; w4.y *= (float)c4.y;
            w4.z *= (float)c4.z; w4.w *= (float)c4.w;
            const float wq[4] = {w4.x, w4.y, w4.z, w4.w};
#pragma unroll
            for (int u = 0; u < 4; ++u) {
                const int k = qq * 4 + u;
                acc[0][k] = fmaf(xv0, wq[u], acc[0][k]);
                acc[1][k] = fmaf(xv1, wq[u], acc[1][k]);
                acc[2][k] = fmaf(xv2, wq[u], acc[2][k]);
                acc[3][k] = fmaf(xv3, wq[u], acc[3][k]);
            }
        }
    }
    __syncthreads();
    for (int idx = t; idx < N_MID; idx += NT) {
        bias_s[idx]  = bias[idx];
        exist_s[idx] = (float)exist[idx];
    }
    __syncthreads();
    int p = 0;
    for (int bb = 0; bb < 64; ++bb) {
#pragma unroll
        for (int kk = 0; kk < 20; ++kk) {
            const int i = bb * 20 + kk;
            const float e = exist_s[i];
            if (e != 0.f) {
                if (cg == bb) {
                    const float bv = bias_s[i];
#pragma unroll
                    for (int a = 0; a < 4; ++a) {
                        const float v = acc[a][kk];
                        const float s = __fdividef(1.f, 1.f + __expf(-v));
                        const float res = (s + bv) * e;
                        res_s[p][rg + 4 * a] = res;
                        if (i >= N_MID - OUT_DIM)
                            out[(size_t)(r0 + rg + 4 * a) * OUT_DIM + (i - (N_MID - OUT_DIM))] = res;
                    }
                }
                __syncthreads();
                const float rv0 = res_s[p][rg];
                const float rv1 = res_s[p][rg + 4];
                const float rv2 = res_s[p][rg + 8];
                const float rv3 = res_s[p][rg + 12];
                const size_t woff = (size_t)(IN_DIM + i) * N_MID + c0;
                if (cg > bb) {
#pragma unroll
                    for (int qq = 0; qq < 5; ++qq) {
                        float4 w4 = *(const float4*)(wsrc + woff + qq * 4);
                        const int4 c4 = *(const int4*)(conn + woff + qq * 4);
                        w4.x *= (float)c4.x; w4.y *= (float)c4.y;
                        w4.z *= (float)c4.z; w4.w *= (float)c4.w;
                        const float wq[4] = {w4.x, w4.y, w4.z, w4.w};
#pragma unroll
                        for (int u = 0; u < 4; ++u) {
                            const int k = qq * 4 + u;
                            acc[0][k] = fmaf(rv0, wq[u], acc[0][k]);
                            acc[1][k] = fmaf(rv1, wq[u], acc[1][k]);
                            acc[2][k] = fmaf(rv2, wq[u], acc[2][k]);
                            acc[3][k] = fmaf(rv3, wq[u], acc[3][k]);
                        }
                    }
                } else if (cg == bb) {
#pragma unroll
                    for (int k = kk + 1; k < 20; ++k) {
                        float ww = wsrc[woff + k] * (float)conn[woff + k];
                        acc[0][k] = fmaf(rv0, ww, acc[0][k]);
                        acc[1][k] = fmaf(rv1, ww, acc[1][k]);
                        acc[2][k] = fmaf(rv2, ww, acc[2][k]);
                        acc[3][k] = fmaf(rv3, ww, acc[3][k]);
                    }
                }
                p ^= 1;
            }
        }
    }
}

extern "C" void kernel_launch(void* const* d_in, const int* in_sizes, int n_in,
                              void* d_out, int out_size, void* d_ws, size_t ws_size,
                              hipStream_t stream) {
    const float* x      = (const float*)d_in[0];
    const float* weight = (const float*)d_in[1];
    const float* bias   = (const float*)d_in[2];
    const int*   conn   = (const int*)d_in[3];
    const int*   exist  = (const int*)d_in[4];
    float*       out    = (float*)d_out;

    if (ws_size >= WS_NEED) {
        char* ws = (char*)d_ws;
        unsigned short* ew2  = (unsigned short*)ws;
        float*          tri  = (float*)(ws + TRI_OFF);
        int*            hdr  = (int*)(ws + HDR_OFF);
        int*            cmap = (int*)(ws + CMAP_OFF);
        int*            ocolp= (int*)(ws + OCOL_OFF);
        float*          bsc  = (float*)(ws + BIASC_OFF);
        unsigned short* bfx  = (unsigned short*)(ws + BFX_OFF);

        build_maps_kernel<<<1, 64, 0, stream>>>(exist, bias, hdr, cmap, ocolp, bsc);
        gather_all_kernel<<<904, NT, 0, stream>>>(weight, conn, hdr, cmap, ew2, tri, bfx);
        net7_kernel<12><<<256, 256, 0, stream>>>(x, ew2, tri, hdr, ocolp, bsc, bfx, out);
        net7_kernel<16><<<256, 256, 0, stream>>>(x, ew2, tri, hdr, ocolp, bsc, bfx, out);
        net_v1_kernel<<<BATCH / 16, NT, 0, stream>>>(x, weight, conn, bias, exist, hdr, out);
    } else {
        net_v1_kernel<<<BATCH / 16, NT, 0, stream>>>(x, weight, conn, bias, exist, nullptr, out);
    }
}